// Round 2
// baseline (1118.355 us; speedup 1.0000x reference)
//
#include <hip/hip_runtime.h>
#include <hip/hip_bf16.h>
#include <cstdint>
#include <cstddef>

#define HIDD 1536
#define NB 32
#define NT 32
#define AD 32
#define NCAT 32
#define MCHUNK 4

typedef __attribute__((ext_vector_type(8))) __bf16 bf16x8;
typedef __attribute__((ext_vector_type(4))) float floatx4;

__device__ __forceinline__ unsigned short f2bf(float f) {
    union { float f; uint32_t u; } v; v.f = f;
    uint32_t r = v.u + 0x7fffu + ((v.u >> 16) & 1u);   // RNE
    return (unsigned short)(r >> 16);
}

__device__ __forceinline__ uint32_t pack2(float lo, float hi) {
    return (uint32_t)f2bf(lo) | ((uint32_t)f2bf(hi) << 16);
}

// ---------------------------------------------------------------------------
// Prep: group samples by cat_id into work items of <=MCHUNK samples.
// items layout (ints): [0..31] cat, [32..63] m, [64..191] smp[item][4], [192] n_items
// ---------------------------------------------------------------------------
__global__ void prep_kernel(const int* __restrict__ cat_ids, int* __restrict__ items) {
    if (threadIdx.x == 0 && blockIdx.x == 0) {
        int n = 0;
        for (int c = 0; c < NCAT; ++c) {
            int lst[NB]; int cnt = 0;
            for (int b = 0; b < NB; ++b) if (cat_ids[b] == c) lst[cnt++] = b;
            for (int off = 0; off < cnt; off += MCHUNK) {
                int m = cnt - off; if (m > MCHUNK) m = MCHUNK;
                items[n]      = c;
                items[32 + n] = m;
                for (int j = 0; j < MCHUNK; ++j)
                    items[64 + n * 4 + j] = (j < m) ? lst[off + j] : 0;
                ++n;
            }
        }
        items[192] = n;
    }
}

// ---------------------------------------------------------------------------
// Kernel 1: x = [actions @ W1[c] + b1[c],  sinusoidal(ts)]   -> bf16 (B,T,3072)
// ---------------------------------------------------------------------------
__global__ __launch_bounds__(256) void build_x_kernel(
    const float* __restrict__ actions,   // (B,T,32)
    const int*   __restrict__ timesteps, // (B,)
    const int*   __restrict__ cat_ids,   // (B,)
    const float* __restrict__ W1,        // (C,32,1536)
    const float* __restrict__ b1,        // (C,1536)
    unsigned short* __restrict__ Xout)   // (B,T,3072) bf16
{
    const int b = blockIdx.z, t = blockIdx.y;
    const int j = blockIdx.x * 256 + threadIdx.x;
    __shared__ float as[AD];
    if (threadIdx.x < AD) as[threadIdx.x] = actions[(b * NT + t) * AD + threadIdx.x];
    __syncthreads();

    float val;
    if (j < HIDD) {
        const int c = cat_ids[b];
        const float* w = W1 + ((size_t)c * AD) * HIDD + j;
        float acc = b1[c * HIDD + j];
        #pragma unroll
        for (int k = 0; k < AD; ++k) acc += as[k] * w[(size_t)k * HIDD];
        val = acc;
    } else {
        const int jj = j - HIDD;
        const int i = jj >> 1;
        const float div = expf(-9.210340371976184f * (float)i * (1.0f / 768.0f));
        const float arg = (float)timesteps[b] * div;
        val = (jj & 1) ? cosf(arg) : sinf(arg);
    }
    Xout[((size_t)(b * NT + t)) * (2 * HIDD) + j] = f2bf(val);
}

// ---------------------------------------------------------------------------
// Grouped GEMM: for work item (cat c, samples smp[0..m)), block covers 64 cols.
//   out[s] = act(X[s] @ W[c] + bias[c])   for each sample s in the item.
// W staged fp32->bf16 transposed [n][k] in LDS, register double-buffered.
// A-fragments (X) read directly from global (LLC-hot).
// ---------------------------------------------------------------------------
template<int K, bool SWISH>
__global__ __launch_bounds__(256) void gemm_grouped_kernel(
    const unsigned short* __restrict__ X,    // (B,32,K) bf16
    const float* __restrict__ W,             // (C,K,1536) fp32
    const float* __restrict__ bias,          // (C,1536) fp32
    const int*   __restrict__ items,
    unsigned short* __restrict__ OutBf,      // used if SWISH
    float* __restrict__ OutF)                // used if !SWISH
{
    const int it = blockIdx.y;
    if (it >= items[192]) return;
    const int c = items[it];
    const int m = items[32 + it];
    int smp[MCHUNK];
    #pragma unroll
    for (int j = 0; j < MCHUNK; ++j) smp[j] = items[64 + it * 4 + j];

    const int n0   = blockIdx.x * 64;
    const int tid  = threadIdx.x;
    const int wave = tid >> 6;
    const int lane = tid & 63;
    const int quad = lane >> 4;
    const int l16  = lane & 15;

    __shared__ __align__(16) unsigned short Ws[64][72];

    floatx4 acc[MCHUNK][2];
    #pragma unroll
    for (int si = 0; si < MCHUNK; ++si)
        #pragma unroll
        for (int rt = 0; rt < 2; ++rt)
            acc[si][rt] = floatx4{0.f, 0.f, 0.f, 0.f};

    // W staging ownership: thread covers k rows q4..q4+3, n cols i4..i4+3
    const int q4 = (tid >> 4) * 4;
    const int i4 = (tid & 15) * 4;
    const float* wbase = W + (size_t)c * K * HIDD + n0 + i4;

    constexpr int KT = K / 64;

    // prefetch k-tile 0
    float4 r0 = *reinterpret_cast<const float4*>(wbase + (size_t)(q4 + 0) * HIDD);
    float4 r1 = *reinterpret_cast<const float4*>(wbase + (size_t)(q4 + 1) * HIDD);
    float4 r2 = *reinterpret_cast<const float4*>(wbase + (size_t)(q4 + 2) * HIDD);
    float4 r3 = *reinterpret_cast<const float4*>(wbase + (size_t)(q4 + 3) * HIDD);

    for (int kb = 0; kb < KT; ++kb) {
        __syncthreads();   // previous iteration's readers are done with Ws
        // convert regs -> Ws[n][k], 4 b64 stores
        {
            uint2 s0 = {pack2(r0.x, r1.x), pack2(r2.x, r3.x)};
            uint2 s1 = {pack2(r0.y, r1.y), pack2(r2.y, r3.y)};
            uint2 s2 = {pack2(r0.z, r1.z), pack2(r2.z, r3.z)};
            uint2 s3 = {pack2(r0.w, r1.w), pack2(r2.w, r3.w)};
            *reinterpret_cast<uint2*>(&Ws[i4 + 0][q4]) = s0;
            *reinterpret_cast<uint2*>(&Ws[i4 + 1][q4]) = s1;
            *reinterpret_cast<uint2*>(&Ws[i4 + 2][q4]) = s2;
            *reinterpret_cast<uint2*>(&Ws[i4 + 3][q4]) = s3;
        }
        // prefetch next k-tile (stays in flight through MFMA phase + barrier)
        if (kb + 1 < KT) {
            const float* wn = wbase + (size_t)((kb + 1) * 64 + q4) * HIDD;
            r0 = *reinterpret_cast<const float4*>(wn);
            r1 = *reinterpret_cast<const float4*>(wn + HIDD);
            r2 = *reinterpret_cast<const float4*>(wn + 2 * HIDD);
            r3 = *reinterpret_cast<const float4*>(wn + 3 * HIDD);
        }
        __syncthreads();   // Ws visible

        // B fragments for this wave's 16 columns
        const bf16x8 bw0 = *reinterpret_cast<const bf16x8*>(&Ws[wave * 16 + l16][0 + quad * 8]);
        const bf16x8 bw1 = *reinterpret_cast<const bf16x8*>(&Ws[wave * 16 + l16][32 + quad * 8]);

        #pragma unroll
        for (int si = 0; si < MCHUNK; ++si) {
            if (si < m) {
                const unsigned short* xr = X + (size_t)(smp[si] * 32) * K + kb * 64 + quad * 8;
                #pragma unroll
                for (int rt = 0; rt < 2; ++rt) {
                    const unsigned short* xp = xr + (size_t)(rt * 16 + l16) * K;
                    const bf16x8 a0 = *reinterpret_cast<const bf16x8*>(xp);
                    const bf16x8 a1 = *reinterpret_cast<const bf16x8*>(xp + 32);
                    acc[si][rt] = __builtin_amdgcn_mfma_f32_16x16x32_bf16(a0, bw0, acc[si][rt], 0, 0, 0);
                    acc[si][rt] = __builtin_amdgcn_mfma_f32_16x16x32_bf16(a1, bw1, acc[si][rt], 0, 0, 0);
                }
            }
        }
    }

    // epilogue: D layout col=lane&15, row=quad*4+reg
    const int n_col = n0 + wave * 16 + l16;
    const float bv = bias[c * HIDD + n_col];
    #pragma unroll
    for (int si = 0; si < MCHUNK; ++si) {
        if (si < m) {
            #pragma unroll
            for (int rt = 0; rt < 2; ++rt) {
                #pragma unroll
                for (int r = 0; r < 4; ++r) {
                    const int row = smp[si] * 32 + rt * 16 + quad * 4 + r;
                    float v = acc[si][rt][r] + bv;
                    if (SWISH) {
                        v = v / (1.f + __expf(-v));
                        OutBf[(size_t)row * HIDD + n_col] = f2bf(v);
                    } else {
                        OutF[(size_t)row * HIDD + n_col] = v;
                    }
                }
            }
        }
    }
}

extern "C" void kernel_launch(void* const* d_in, const int* in_sizes, int n_in,
                              void* d_out, int out_size, void* d_ws, size_t ws_size,
                              hipStream_t stream) {
    (void)in_sizes; (void)n_in; (void)out_size; (void)ws_size;
    const float* actions   = (const float*)d_in[0];
    const int*   timesteps = (const int*)d_in[1];
    const int*   cat_ids   = (const int*)d_in[2];
    const float* W1        = (const float*)d_in[3];
    const float* b1        = (const float*)d_in[4];
    const float* W2        = (const float*)d_in[5];
    const float* b2        = (const float*)d_in[6];
    const float* W3        = (const float*)d_in[7];
    const float* b3        = (const float*)d_in[8];
    float* out = (float*)d_out;

    int* items = (int*)d_ws;                                      // 256 ints
    unsigned short* xbuf = (unsigned short*)d_ws + 512;           // B*T*3072 bf16
    unsigned short* hbuf = xbuf + (size_t)NB * NT * 2 * HIDD;     // B*T*1536 bf16

    prep_kernel<<<1, 64, 0, stream>>>(cat_ids, items);

    build_x_kernel<<<dim3(12, NT, NB), 256, 0, stream>>>(
        actions, timesteps, cat_ids, W1, b1, xbuf);

    gemm_grouped_kernel<2 * HIDD, true><<<dim3(24, 32), 256, 0, stream>>>(
        xbuf, W2, b2, items, hbuf, nullptr);

    gemm_grouped_kernel<HIDD, false><<<dim3(24, 32), 256, 0, stream>>>(
        hbuf, W3, b3, items, nullptr, out);
}